// Round 1
// baseline (2148.325 us; speedup 1.0000x reference)
//
#include <hip/hip_runtime.h>
#include <math.h>

namespace {
constexpr int NDFT   = 1024;
constexpr int NHOP   = 256;
constexpr int NFILT  = 513;
constexpr int LSRC   = 262144;
constexpr int NFRAME = 1024;
constexpr int TILE_F = 32;
constexpr int SPAN   = (TILE_F - 1) * NHOP + NDFT;  // 8960 floats = 35 KiB LDS
constexpr int PAD_L  = 384;
constexpr long PER_B = (long)NFILT * NFRAME * 2;    // 1,050,624 elems per batch item
}

__device__ __forceinline__ unsigned int f2key(float f) {
    unsigned int u = __float_as_uint(f);
    return (u & 0x80000000u) ? ~u : (u | 0x80000000u);
}
__device__ __forceinline__ float key2f(unsigned int k) {
    return (k & 0x80000000u) ? __uint_as_float(k ^ 0x80000000u) : __uint_as_float(~k);
}

__global__ void zero_ws(unsigned int* __restrict__ w) {
    if (threadIdx.x < 32) w[threadIdx.x] = 0u;
}

// Each block: one signal s (0..63), 32 consecutive frames, bins 0..511.
// Thread tid owns bins {tid, tid+256}; accumulates re/im over all 1024 taps.
__global__ __launch_bounds__(256) void spec_main(
    const float* __restrict__ x, const float* __restrict__ kr,
    const float* __restrict__ ki, float* __restrict__ out,
    unsigned int* __restrict__ wmax)
{
    __shared__ float xs[SPAN];
    const int s   = blockIdx.x;          // signal index 0..63
    const int f0  = blockIdx.y * TILE_F; // first frame of tile
    const int tid = threadIdx.x;
    const long sig_base = (long)s * LSRC;
    const int start = f0 * NHOP - PAD_L;

    // Stage the shared x window (8960 floats) with zero-padding at edges.
    for (int i = tid; i < SPAN; i += 256) {
        const int p = start + i;
        xs[i] = (p >= 0 && p < LSRC) ? x[sig_base + p] : 0.0f;
    }
    __syncthreads();

    const int b0 = tid;
    const int b1 = tid + 256;

    float ar0[TILE_F], ai0[TILE_F], ar1[TILE_F], ai1[TILE_F];
    #pragma unroll
    for (int f = 0; f < TILE_F; ++f) { ar0[f] = 0.f; ai0[f] = 0.f; ar1[f] = 0.f; ai1[f] = 0.f; }

    #pragma unroll 1
    for (int t = 0; t < NDFT; t += 4) {
        float br0[4], bq0[4], br1[4], bq1[4];
        #pragma unroll
        for (int j = 0; j < 4; ++j) {
            br0[j] = kr[(t + j) * NFILT + b0];
            bq0[j] = ki[(t + j) * NFILT + b0];
            br1[j] = kr[(t + j) * NFILT + b1];
            bq1[j] = ki[(t + j) * NFILT + b1];
        }
        #pragma unroll
        for (int f = 0; f < TILE_F; ++f) {
            const float4 a = *reinterpret_cast<const float4*>(&xs[t + NHOP * f]);
            ar0[f] = fmaf(a.x, br0[0], ar0[f]);
            ar0[f] = fmaf(a.y, br0[1], ar0[f]);
            ar0[f] = fmaf(a.z, br0[2], ar0[f]);
            ar0[f] = fmaf(a.w, br0[3], ar0[f]);
            ai0[f] = fmaf(a.x, bq0[0], ai0[f]);
            ai0[f] = fmaf(a.y, bq0[1], ai0[f]);
            ai0[f] = fmaf(a.z, bq0[2], ai0[f]);
            ai0[f] = fmaf(a.w, bq0[3], ai0[f]);
            ar1[f] = fmaf(a.x, br1[0], ar1[f]);
            ar1[f] = fmaf(a.y, br1[1], ar1[f]);
            ar1[f] = fmaf(a.z, br1[2], ar1[f]);
            ar1[f] = fmaf(a.w, br1[3], ar1[f]);
            ai1[f] = fmaf(a.x, bq1[0], ai1[f]);
            ai1[f] = fmaf(a.y, bq1[1], ai1[f]);
            ai1[f] = fmaf(a.z, bq1[2], ai1[f]);
            ai1[f] = fmaf(a.w, bq1[3], ai1[f]);
        }
    }

    // Epilogue: power -> dB, write out, block max -> atomicMax per batch item.
    const int b  = s >> 1;
    const int ch = s & 1;
    float lmax = -3.0e38f;
    #pragma unroll
    for (int f = 0; f < TILE_F; ++f) {
        const int frame = f0 + f;
        const float p0 = ar0[f] * ar0[f] + ai0[f] * ai0[f];
        const float p1 = ar1[f] * ar1[f] + ai1[f] * ai1[f];
        const float d0 = 10.0f * log10f(fmaxf(p0, 1e-10f));
        const float d1 = 10.0f * log10f(fmaxf(p1, 1e-10f));
        lmax = fmaxf(lmax, fmaxf(d0, d1));
        out[((long)(b * NFILT + b0) * NFRAME + frame) * 2 + ch] = d0;
        out[((long)(b * NFILT + b1) * NFRAME + frame) * 2 + ch] = d1;
    }
    #pragma unroll
    for (int off = 32; off > 0; off >>= 1) lmax = fmaxf(lmax, __shfl_xor(lmax, off));
    if ((tid & 63) == 0) atomicMax(&wmax[b], f2key(lmax));
}

// Nyquist bin (512) for all 64 signals x 1024 frames. One thread per frame.
__global__ __launch_bounds__(256) void spec_nyq(
    const float* __restrict__ x, const float* __restrict__ kr,
    const float* __restrict__ ki, float* __restrict__ out,
    unsigned int* __restrict__ wmax)
{
    const int gid   = blockIdx.x * 256 + threadIdx.x;  // 0..65535
    const int s     = gid >> 10;
    const int frame = gid & 1023;
    const float* xp = x + (long)s * LSRC;
    const int start = frame * NHOP - PAD_L;
    float re = 0.f, im = 0.f;
    for (int t = 0; t < NDFT; ++t) {
        const int idx = start + t;
        const float a = (idx >= 0 && idx < LSRC) ? xp[idx] : 0.0f;
        re = fmaf(a, kr[t * NFILT + 512], re);
        im = fmaf(a, ki[t * NFILT + 512], im);
    }
    const float p = re * re + im * im;
    const float d = 10.0f * log10f(fmaxf(p, 1e-10f));
    const int b = s >> 1, ch = s & 1;
    out[((long)(b * NFILT + 512) * NFRAME + frame) * 2 + ch] = d;
    float lmax = d;
    #pragma unroll
    for (int off = 32; off > 0; off >>= 1) lmax = fmaxf(lmax, __shfl_xor(lmax, off));
    if ((threadIdx.x & 63) == 0) atomicMax(&wmax[b], f2key(lmax));
}

// out = max(out - max_b, -80), vectorized float4; PER_B divisible by 4.
__global__ __launch_bounds__(256) void finalize(
    float* __restrict__ out, const unsigned int* __restrict__ wmax, long n4)
{
    const long stride = (long)gridDim.x * 256;
    for (long i4 = blockIdx.x * 256L + threadIdx.x; i4 < n4; i4 += stride) {
        const long i = i4 * 4;
        const int b  = (int)(i / PER_B);
        const float m = key2f(wmax[b]);
        float4 v = reinterpret_cast<float4*>(out)[i4];
        v.x = fmaxf(v.x - m, -80.0f);
        v.y = fmaxf(v.y - m, -80.0f);
        v.z = fmaxf(v.z - m, -80.0f);
        v.w = fmaxf(v.w - m, -80.0f);
        reinterpret_cast<float4*>(out)[i4] = v;
    }
}

extern "C" void kernel_launch(void* const* d_in, const int* in_sizes, int n_in,
                              void* d_out, int out_size, void* d_ws, size_t ws_size,
                              hipStream_t stream) {
    const float* x  = (const float*)d_in[0];
    const float* kr = (const float*)d_in[1];
    const float* ki = (const float*)d_in[2];
    float* out = (float*)d_out;
    unsigned int* wmax = (unsigned int*)d_ws;

    zero_ws<<<1, 64, 0, stream>>>(wmax);
    dim3 grid(64, NFRAME / TILE_F);  // 64 signals x 32 frame-tiles
    spec_main<<<grid, 256, 0, stream>>>(x, kr, ki, out, wmax);
    spec_nyq<<<(64 * NFRAME) / 256, 256, 0, stream>>>(x, kr, ki, out, wmax);
    const long n4 = (long)out_size / 4;
    finalize<<<2048, 256, 0, stream>>>(out, wmax, n4);
}

// Round 2
// 729.516 us; speedup vs baseline: 2.9449x; 2.9449x over previous
//
#include <hip/hip_runtime.h>
#include <math.h>

namespace {
constexpr int NDFT   = 1024;
constexpr int NHOP   = 256;
constexpr int NFILT  = 513;
constexpr int LSRC   = 262144;
constexpr int NFRAME = 1024;
constexpr int PAD_L  = 384;
constexpr long PER_B = (long)NFILT * NFRAME * 2;

constexpr int BT = 9;            // bin-tiles of 64 bins (tile 8 = Nyquist + pad)
constexpr int KT = 16;           // K-tiles of 64 taps
constexpr int CHUNK_US = 16384;  // ushorts per (bt,kt) chunk: [hl2][n128][k64]
constexpr size_t WS_B_BYTES = (size_t)BT * KT * CHUNK_US * 2;  // 4,718,592
}

using short8 = __attribute__((ext_vector_type(8))) short;
using f32x4  = __attribute__((ext_vector_type(4))) float;

__device__ __forceinline__ unsigned int f2key(float f) {
    unsigned int u = __float_as_uint(f);
    return (u & 0x80000000u) ? ~u : (u | 0x80000000u);
}
__device__ __forceinline__ float key2f(unsigned int k) {
    return (k & 0x80000000u) ? __uint_as_float(k ^ 0x80000000u) : __uint_as_float(~k);
}
__device__ __forceinline__ unsigned short bf16rn(float v) {
    unsigned int u = __float_as_uint(v);
    return (unsigned short)((u + 0x7fffu + ((u >> 16) & 1u)) >> 16);
}

__global__ void zero_ws(unsigned int* __restrict__ w) {
    if (threadIdx.x < 32) w[threadIdx.x] = 0u;
}

// ---------------------------------------------------------------------------
// Precompute: DFT kernels -> transposed [n][k], split hi/lo bf16, XOR-swizzled
// chunks of 32KB per (bt,kt), ready for linear global_load_lds staging.
// n = local_bin*2 + isim  (re/im interleaved in adjacent columns)
// ---------------------------------------------------------------------------
__global__ __launch_bounds__(256) void build_B(const float* __restrict__ kr,
                                               const float* __restrict__ ki,
                                               unsigned short* __restrict__ wsB)
{
    const int bt = blockIdx.x / KT;
    const int kt = blockIdx.x % KT;
    unsigned short* chunk = wsB + (size_t)blockIdx.x * CHUNK_US;
    for (int s = 0; s < 4; ++s) {
        const int local = s * 256 + threadIdx.x;  // 0..1023
        const int n  = local >> 3;                // 0..127
        const int kq = local & 7;                 // 16B slot within row
        const int bin = bt * 64 + (n >> 1);
        const float* src = (n & 1) ? ki : kr;
        union { unsigned short u[8]; uint4 v; } ph, pl;
        #pragma unroll
        for (int i = 0; i < 8; ++i) {
            const int t = kt * 64 + kq * 8 + i;
            const float v = (bin < NFILT) ? src[t * NFILT + bin] : 0.0f;
            const unsigned short h = bf16rn(v);
            ph.u[i] = h;
            pl.u[i] = bf16rn(v - __uint_as_float((unsigned int)h << 16));
        }
        const int idx = n * 64 + ((kq ^ (n & 7)) << 3);
        *reinterpret_cast<uint4*>(&chunk[idx])        = ph.v;
        *reinterpret_cast<uint4*>(&chunk[8192 + idx]) = pl.v;
    }
}

// ---------------------------------------------------------------------------
// Split-bf16 MFMA GEMM: block = 64 frames x 128 cols, K=1024 in 16 steps.
// 8 waves (2M x 4N), wave-tile 32x32 = 2x2 frags of 16x16x32_bf16.
// C += Ah*Bh + Ah*Bl + Al*Bh   (al*bl ~ 2^-18 dropped)
// ---------------------------------------------------------------------------
__global__ __launch_bounds__(512, 4) void spec_gemm(
    const float* __restrict__ x, const unsigned short* __restrict__ wsB,
    float* __restrict__ out, unsigned int* __restrict__ wmax)
{
    __shared__ unsigned short Ad[2 * 4096];  // [hl][row64][k64 swz]
    __shared__ unsigned short Bd[2 * 8192];  // [hl][n128][k64 swz]

    const int tid  = threadIdx.x;
    const int lane = tid & 63, w = tid >> 6;
    const int wm = w >> 2, wn = w & 3;
    const int l15 = lane & 15, l16 = lane >> 4;
    const int sig = blockIdx.x >> 4, ft = blockIdx.x & 15;
    const int bt  = blockIdx.y;
    const int f0  = ft * 64;
    const long sb = (long)sig * LSRC;

    const int arow = tid >> 3, akq = tid & 7;
    const int pbase = (f0 + arow) * NHOP - PAD_L + akq * 8;
    const int awr = arow * 64 + ((akq ^ (arow & 7)) << 3);
    const unsigned short* bchunk = wsB + (size_t)(bt * KT) * CHUNK_US;

    f32x4 acc[2][2];
    #pragma unroll
    for (int i = 0; i < 2; ++i)
        #pragma unroll
        for (int j = 0; j < 2; ++j)
            #pragma unroll
            for (int r = 0; r < 4; ++r) acc[i][j][r] = 0.0f;

    #pragma unroll 1
    for (int kt = 0; kt < KT; ++kt) {
        // --- stage B: linear async copy of pre-swizzled chunk (32KB) ---
        const char* gB = (const char*)(bchunk + (size_t)kt * CHUNK_US);
        #pragma unroll
        for (int r = 0; r < 4; ++r) {
            const int wo = r * 8192 + w * 1024;
            __builtin_amdgcn_global_load_lds(
                (const __attribute__((address_space(1))) unsigned int*)(gB + wo + lane * 16),
                (__attribute__((address_space(3))) unsigned int*)((char*)Bd + wo),
                16, 0, 0);
        }
        // --- stage A: 8 fp32 from x, split hi/lo, swizzled ds_write ---
        const int p0 = pbase + kt * 64;
        float va[8];
        if (p0 >= 0 && p0 + 8 <= LSRC) {
            const float4 t0 = *reinterpret_cast<const float4*>(x + sb + p0);
            const float4 t1 = *reinterpret_cast<const float4*>(x + sb + p0 + 4);
            va[0] = t0.x; va[1] = t0.y; va[2] = t0.z; va[3] = t0.w;
            va[4] = t1.x; va[5] = t1.y; va[6] = t1.z; va[7] = t1.w;
        } else {
            #pragma unroll
            for (int i = 0; i < 8; ++i) {
                const int p = p0 + i;
                va[i] = (p >= 0 && p < LSRC) ? x[sb + p] : 0.0f;
            }
        }
        union { unsigned short u[8]; uint4 v; } ph, pl;
        #pragma unroll
        for (int i = 0; i < 8; ++i) {
            const unsigned short h = bf16rn(va[i]);
            ph.u[i] = h;
            pl.u[i] = bf16rn(va[i] - __uint_as_float((unsigned int)h << 16));
        }
        *reinterpret_cast<uint4*>(&Ad[awr])        = ph.v;
        *reinterpret_cast<uint4*>(&Ad[4096 + awr]) = pl.v;
        __syncthreads();

        // --- compute: 2 k-substeps x 2x2 frags x 3 split products ---
        #pragma unroll
        for (int ks = 0; ks < 2; ++ks) {
            const int slot = ks * 4 + l16;
            short8 ah[2], al[2], bh[2], bl[2];
            #pragma unroll
            for (int mf = 0; mf < 2; ++mf) {
                const int r = wm * 32 + mf * 16 + l15;
                const int idx = r * 64 + ((slot ^ (r & 7)) << 3);
                ah[mf] = *reinterpret_cast<const short8*>(&Ad[idx]);
                al[mf] = *reinterpret_cast<const short8*>(&Ad[4096 + idx]);
            }
            #pragma unroll
            for (int nf = 0; nf < 2; ++nf) {
                const int n = wn * 32 + nf * 16 + l15;
                const int idx = n * 64 + ((slot ^ (n & 7)) << 3);
                bh[nf] = *reinterpret_cast<const short8*>(&Bd[idx]);
                bl[nf] = *reinterpret_cast<const short8*>(&Bd[8192 + idx]);
            }
            #pragma unroll
            for (int mf = 0; mf < 2; ++mf)
                #pragma unroll
                for (int nf = 0; nf < 2; ++nf) {
                    acc[mf][nf] = __builtin_amdgcn_mfma_f32_16x16x32_bf16(ah[mf], bh[nf], acc[mf][nf], 0, 0, 0);
                    acc[mf][nf] = __builtin_amdgcn_mfma_f32_16x16x32_bf16(ah[mf], bl[nf], acc[mf][nf], 0, 0, 0);
                    acc[mf][nf] = __builtin_amdgcn_mfma_f32_16x16x32_bf16(al[mf], bh[nf], acc[mf][nf], 0, 0, 0);
                }
        }
        __syncthreads();
    }

    // --- epilogue: power -> dB -> store + per-batch max ---
    const int batch = sig >> 1, ch = sig & 1;
    float lmax = -3.0e38f;
    #pragma unroll
    for (int mf = 0; mf < 2; ++mf)
        #pragma unroll
        for (int nf = 0; nf < 2; ++nf) {
            const int n = wn * 32 + nf * 16 + l15;
            const int bin = bt * 64 + (n >> 1);
            #pragma unroll
            for (int r = 0; r < 4; ++r) {
                const float v  = acc[mf][nf][r];
                const float sq = v * v;
                const float p  = sq + __shfl_xor(sq, 1);
                if (!(lane & 1) && bin < NFILT) {
                    const int frame = f0 + wm * 32 + mf * 16 + l16 * 4 + r;
                    const float d = 10.0f * log10f(fmaxf(p, 1e-10f));
                    out[((long)(batch * NFILT + bin) * NFRAME + frame) * 2 + ch] = d;
                    lmax = fmaxf(lmax, d);
                }
            }
        }
    #pragma unroll
    for (int off = 32; off > 0; off >>= 1) lmax = fmaxf(lmax, __shfl_xor(lmax, off));
    if (lane == 0) atomicMax(&wmax[batch], f2key(lmax));
}

// out = max(out - max_b, -80), vectorized float4
__global__ __launch_bounds__(256) void finalize(
    float* __restrict__ out, const unsigned int* __restrict__ wmax, long n4)
{
    const long stride = (long)gridDim.x * 256;
    for (long i4 = blockIdx.x * 256L + threadIdx.x; i4 < n4; i4 += stride) {
        const long i = i4 * 4;
        const int b  = (int)(i / PER_B);
        const float m = key2f(wmax[b]);
        float4 v = reinterpret_cast<float4*>(out)[i4];
        v.x = fmaxf(v.x - m, -80.0f);
        v.y = fmaxf(v.y - m, -80.0f);
        v.z = fmaxf(v.z - m, -80.0f);
        v.w = fmaxf(v.w - m, -80.0f);
        reinterpret_cast<float4*>(out)[i4] = v;
    }
}

// ---------------------------------------------------------------------------
// Fallback path (proven-correct fp32 vector version) if ws is too small.
// ---------------------------------------------------------------------------
namespace fb {
constexpr int TILE_F = 32;
constexpr int SPAN   = (TILE_F - 1) * NHOP + NDFT;
}

__global__ __launch_bounds__(256) void spec_main_fb(
    const float* __restrict__ x, const float* __restrict__ kr,
    const float* __restrict__ ki, float* __restrict__ out,
    unsigned int* __restrict__ wmax)
{
    __shared__ float xs[fb::SPAN];
    const int s   = blockIdx.x;
    const int f0  = blockIdx.y * fb::TILE_F;
    const int tid = threadIdx.x;
    const long sig_base = (long)s * LSRC;
    const int start = f0 * NHOP - PAD_L;
    for (int i = tid; i < fb::SPAN; i += 256) {
        const int p = start + i;
        xs[i] = (p >= 0 && p < LSRC) ? x[sig_base + p] : 0.0f;
    }
    __syncthreads();
    const int b0 = tid, b1 = tid + 256;
    float ar0[fb::TILE_F], ai0[fb::TILE_F], ar1[fb::TILE_F], ai1[fb::TILE_F];
    #pragma unroll
    for (int f = 0; f < fb::TILE_F; ++f) { ar0[f]=0.f; ai0[f]=0.f; ar1[f]=0.f; ai1[f]=0.f; }
    #pragma unroll 1
    for (int t = 0; t < NDFT; t += 4) {
        float br0[4], bq0[4], br1[4], bq1[4];
        #pragma unroll
        for (int j = 0; j < 4; ++j) {
            br0[j] = kr[(t + j) * NFILT + b0]; bq0[j] = ki[(t + j) * NFILT + b0];
            br1[j] = kr[(t + j) * NFILT + b1]; bq1[j] = ki[(t + j) * NFILT + b1];
        }
        #pragma unroll
        for (int f = 0; f < fb::TILE_F; ++f) {
            const float4 a = *reinterpret_cast<const float4*>(&xs[t + NHOP * f]);
            ar0[f]=fmaf(a.x,br0[0],ar0[f]); ar0[f]=fmaf(a.y,br0[1],ar0[f]);
            ar0[f]=fmaf(a.z,br0[2],ar0[f]); ar0[f]=fmaf(a.w,br0[3],ar0[f]);
            ai0[f]=fmaf(a.x,bq0[0],ai0[f]); ai0[f]=fmaf(a.y,bq0[1],ai0[f]);
            ai0[f]=fmaf(a.z,bq0[2],ai0[f]); ai0[f]=fmaf(a.w,bq0[3],ai0[f]);
            ar1[f]=fmaf(a.x,br1[0],ar1[f]); ar1[f]=fmaf(a.y,br1[1],ar1[f]);
            ar1[f]=fmaf(a.z,br1[2],ar1[f]); ar1[f]=fmaf(a.w,br1[3],ar1[f]);
            ai1[f]=fmaf(a.x,bq1[0],ai1[f]); ai1[f]=fmaf(a.y,bq1[1],ai1[f]);
            ai1[f]=fmaf(a.z,bq1[2],ai1[f]); ai1[f]=fmaf(a.w,bq1[3],ai1[f]);
        }
    }
    const int b = s >> 1, ch = s & 1;
    float lmax = -3.0e38f;
    #pragma unroll
    for (int f = 0; f < fb::TILE_F; ++f) {
        const int frame = f0 + f;
        const float p0 = ar0[f]*ar0[f] + ai0[f]*ai0[f];
        const float p1 = ar1[f]*ar1[f] + ai1[f]*ai1[f];
        const float d0 = 10.0f * log10f(fmaxf(p0, 1e-10f));
        const float d1 = 10.0f * log10f(fmaxf(p1, 1e-10f));
        lmax = fmaxf(lmax, fmaxf(d0, d1));
        out[((long)(b * NFILT + b0) * NFRAME + frame) * 2 + ch] = d0;
        out[((long)(b * NFILT + b1) * NFRAME + frame) * 2 + ch] = d1;
    }
    #pragma unroll
    for (int off = 32; off > 0; off >>= 1) lmax = fmaxf(lmax, __shfl_xor(lmax, off));
    if ((tid & 63) == 0) atomicMax(&wmax[b], f2key(lmax));
}

__global__ __launch_bounds__(256) void spec_nyq_fb(
    const float* __restrict__ x, const float* __restrict__ kr,
    const float* __restrict__ ki, float* __restrict__ out,
    unsigned int* __restrict__ wmax)
{
    const int gid   = blockIdx.x * 256 + threadIdx.x;
    const int s     = gid >> 10;
    const int frame = gid & 1023;
    const float* xp = x + (long)s * LSRC;
    const int start = frame * NHOP - PAD_L;
    float re = 0.f, im = 0.f;
    for (int t = 0; t < NDFT; ++t) {
        const int idx = start + t;
        const float a = (idx >= 0 && idx < LSRC) ? xp[idx] : 0.0f;
        re = fmaf(a, kr[t * NFILT + 512], re);
        im = fmaf(a, ki[t * NFILT + 512], im);
    }
    const float p = re * re + im * im;
    const float d = 10.0f * log10f(fmaxf(p, 1e-10f));
    const int b = s >> 1, ch = s & 1;
    out[((long)(b * NFILT + 512) * NFRAME + frame) * 2 + ch] = d;
    float lmax = d;
    #pragma unroll
    for (int off = 32; off > 0; off >>= 1) lmax = fmaxf(lmax, __shfl_xor(lmax, off));
    if ((threadIdx.x & 63) == 0) atomicMax(&wmax[b], f2key(lmax));
}

extern "C" void kernel_launch(void* const* d_in, const int* in_sizes, int n_in,
                              void* d_out, int out_size, void* d_ws, size_t ws_size,
                              hipStream_t stream) {
    const float* x  = (const float*)d_in[0];
    const float* kr = (const float*)d_in[1];
    const float* ki = (const float*)d_in[2];
    float* out = (float*)d_out;
    const long n4 = (long)out_size / 4;

    if (ws_size >= WS_B_BYTES + 128) {
        unsigned short* wsB = (unsigned short*)d_ws;
        unsigned int* wmax  = (unsigned int*)((char*)d_ws + WS_B_BYTES);
        zero_ws<<<1, 64, 0, stream>>>(wmax);
        build_B<<<BT * KT, 256, 0, stream>>>(kr, ki, wsB);
        spec_gemm<<<dim3(1024, BT), 512, 0, stream>>>(x, wsB, out, wmax);
        finalize<<<2048, 256, 0, stream>>>(out, wmax, n4);
    } else {
        unsigned int* wmax = (unsigned int*)d_ws;
        zero_ws<<<1, 64, 0, stream>>>(wmax);
        dim3 grid(64, NFRAME / fb::TILE_F);
        spec_main_fb<<<grid, 256, 0, stream>>>(x, kr, ki, out, wmax);
        spec_nyq_fb<<<(64 * NFRAME) / 256, 256, 0, stream>>>(x, kr, ki, out, wmax);
        finalize<<<2048, 256, 0, stream>>>(out, wmax, n4);
    }
}

// Round 3
// 683.610 us; speedup vs baseline: 3.1426x; 1.0672x over previous
//
#include <hip/hip_runtime.h>
#include <math.h>

namespace {
constexpr int NDFT   = 1024;
constexpr int NHOP   = 256;
constexpr int NFILT  = 513;
constexpr int LSRC   = 262144;
constexpr int NFRAME = 1024;
constexpr int PAD_L  = 384;
constexpr long PER_B = (long)NFILT * NFRAME * 2;

constexpr int NT = 8;                 // col-tiles of 128 cols (64 bins re/im)
constexpr int KT = 32;                // K-tiles of 32 taps
constexpr int CHUNK_US = 8192;        // ushorts per (nt,kt) chunk = 16 KB
constexpr size_t WS_B_BYTES = (size_t)NT * KT * CHUNK_US * 2;  // 4 MiB
}

using short8 = __attribute__((ext_vector_type(8))) short;
using f32x4  = __attribute__((ext_vector_type(4))) float;

__device__ __forceinline__ unsigned int f2key(float f) {
    unsigned int u = __float_as_uint(f);
    return (u & 0x80000000u) ? ~u : (u | 0x80000000u);
}
__device__ __forceinline__ float key2f(unsigned int k) {
    return (k & 0x80000000u) ? __uint_as_float(k ^ 0x80000000u) : __uint_as_float(~k);
}
__device__ __forceinline__ unsigned short bf16rn(float v) {
    unsigned int u = __float_as_uint(v);
    return (unsigned short)((u + 0x7fffu + ((u >> 16) & 1u)) >> 16);
}

__global__ void zero_ws(unsigned int* __restrict__ w) {
    if (threadIdx.x < 32) w[threadIdx.x] = 0u;
}

// ---------------------------------------------------------------------------
// Precompute B: DFT kernels -> [col][slot^(col&7)][8] bf16 hi/lo chunks of
// 16 KB per (nt,kt), the exact LDS image for linear global_load_lds staging.
// col = local_bin*2 + isim; slot 0-3 = hi octets, 4-7 = lo octets.
// ---------------------------------------------------------------------------
__global__ __launch_bounds__(256) void build_B(const float* __restrict__ kr,
                                               const float* __restrict__ ki,
                                               unsigned short* __restrict__ wsB)
{
    const int nt = blockIdx.x >> 5;
    const int kt = blockIdx.x & 31;
    unsigned short* chunk = wsB + (size_t)blockIdx.x * CHUNK_US;
    const int col = threadIdx.x >> 1;        // 0..127
    const int h   = threadIdx.x & 1;         // 0 = hi slots, 1 = lo slots
    const int bin = nt * 64 + (col >> 1);    // < 512
    const float* src = (col & 1) ? ki : kr;
    #pragma unroll
    for (int j = 0; j < 4; ++j) {
        const int sl = h * 4 + j;            // unswizzled slot
        const int c  = sl & 3;               // tap octet
        union { unsigned short u[8]; uint4 v; } pk;
        #pragma unroll
        for (int i = 0; i < 8; ++i) {
            const int t = kt * 32 + c * 8 + i;
            const float v = src[t * NFILT + bin];
            const unsigned short hi = bf16rn(v);
            pk.u[i] = h ? bf16rn(v - __uint_as_float((unsigned int)hi << 16)) : hi;
        }
        *reinterpret_cast<uint4*>(&chunk[col * 64 + ((sl ^ (col & 7)) << 3)]) = pk.v;
    }
}

// ---------------------------------------------------------------------------
// Split-bf16 MFMA GEMM: block = 128 frames x 128 cols, 4 waves (2M x 2N),
// wave-tile 64x64 = 4x4 frags of 16x16x32_bf16, double-buffered kt=32.
// C += Ah*Bh + Al*Bh + Ah*Bl    (al*bl ~ 2^-18 dropped)
// ---------------------------------------------------------------------------
__global__ __launch_bounds__(256, 2) void spec_gemm(
    const float* __restrict__ x, const unsigned short* __restrict__ wsB,
    float* __restrict__ out, unsigned int* __restrict__ wmax)
{
    __shared__ unsigned short Ad[2][128][64];  // [buf][row][slot(8)x8] 32 KB
    __shared__ unsigned short Bd[2][128][64];  // [buf][col][slot(8)x8] 32 KB

    const int tid  = threadIdx.x;
    const int lane = tid & 63, w = tid >> 6;
    const int wm = w >> 1, wn = w & 1;
    const int l15 = lane & 15, l16 = lane >> 4;
    const int mt = blockIdx.x, nt = blockIdx.y;
    const int sig = mt >> 3, f0 = (mt & 7) * 128;
    const long sb = (long)sig * LSRC;

    const int arow = tid >> 1, ac2 = tid & 1;      // A staging: row, 16-tap half
    const int abase_p = (f0 + arow) * NHOP - PAD_L + ac2 * 16;
    const unsigned short* bchunks = wsB + (size_t)nt * KT * CHUNK_US;

    f32x4 acc[4][4];
    #pragma unroll
    for (int i = 0; i < 4; ++i)
        #pragma unroll
        for (int j = 0; j < 4; ++j)
            #pragma unroll
            for (int r = 0; r < 4; ++r) acc[i][j][r] = 0.0f;

    float va[16];

    #define LOAD_A(ktv)                                                        \
        {                                                                      \
            const int p0 = abase_p + (ktv) * 32;                               \
            if (p0 >= 0 && p0 + 16 <= LSRC) {                                  \
                *reinterpret_cast<float4*>(&va[0])  = *reinterpret_cast<const float4*>(x + sb + p0);      \
                *reinterpret_cast<float4*>(&va[4])  = *reinterpret_cast<const float4*>(x + sb + p0 + 4);  \
                *reinterpret_cast<float4*>(&va[8])  = *reinterpret_cast<const float4*>(x + sb + p0 + 8);  \
                *reinterpret_cast<float4*>(&va[12]) = *reinterpret_cast<const float4*>(x + sb + p0 + 12); \
            } else {                                                           \
                _Pragma("unroll")                                              \
                for (int i = 0; i < 16; ++i) {                                 \
                    const int p = p0 + i;                                      \
                    va[i] = (p >= 0 && p < LSRC) ? x[sb + p] : 0.0f;           \
                }                                                              \
            }                                                                  \
        }

    #define LOAD_B(ktv, nb)                                                    \
        {                                                                      \
            const char* g = (const char*)(bchunks + (size_t)(ktv) * CHUNK_US); \
            char* l = (char*)&Bd[nb][0][0];                                    \
            _Pragma("unroll")                                                  \
            for (int i = 0; i < 4; ++i) {                                      \
                const int off = i * 4096 + w * 1024;                           \
                __builtin_amdgcn_global_load_lds(                              \
                    (const __attribute__((address_space(1))) unsigned int*)(g + off + lane * 16), \
                    (__attribute__((address_space(3))) unsigned int*)(l + off), \
                    16, 0, 0);                                                 \
            }                                                                  \
        }

    #define WRITE_A(nb)                                                       \
        {                                                                      \
            unsigned short* ab = &Ad[nb][arow][0];                             \
            _Pragma("unroll")                                                  \
            for (int j = 0; j < 2; ++j) {                                      \
                union { unsigned short u[8]; uint4 v; } hv, lv;                \
                _Pragma("unroll")                                              \
                for (int i = 0; i < 8; ++i) {                                  \
                    const float vv = va[j * 8 + i];                            \
                    const unsigned short hi = bf16rn(vv);                      \
                    hv.u[i] = hi;                                              \
                    lv.u[i] = bf16rn(vv - __uint_as_float((unsigned int)hi << 16)); \
                }                                                              \
                const int c = ac2 * 2 + j;                                     \
                *reinterpret_cast<uint4*>(ab + (((c) ^ (arow & 7)) << 3))     = hv.v; \
                *reinterpret_cast<uint4*>(ab + (((4 + c) ^ (arow & 7)) << 3)) = lv.v; \
            }                                                                  \
        }

    // prologue: stage kt=0 into buffer 0
    LOAD_A(0)
    LOAD_B(0, 0)
    WRITE_A(0)
    __syncthreads();

    #pragma unroll 1
    for (int kt = 0; kt < KT; ++kt) {
        const int cur = kt & 1, nxt = cur ^ 1;
        const bool pf = (kt + 1 < KT);
        if (pf) {
            LOAD_A(kt + 1)
            LOAD_B(kt + 1, nxt)
        }

        short8 ah[4], al[4];
        #pragma unroll
        for (int mf = 0; mf < 4; ++mf) {
            const int row = wm * 64 + mf * 16 + l15;
            const unsigned short* ab = &Ad[cur][row][0];
            ah[mf] = *reinterpret_cast<const short8*>(ab + ((l16 ^ (row & 7)) << 3));
            al[mf] = *reinterpret_cast<const short8*>(ab + (((4 + l16) ^ (row & 7)) << 3));
        }
        __builtin_amdgcn_s_setprio(1);
        #pragma unroll
        for (int nf = 0; nf < 4; ++nf) {
            const int col = wn * 64 + nf * 16 + l15;
            const unsigned short* bb = &Bd[cur][col][0];
            const short8 bh = *reinterpret_cast<const short8*>(bb + ((l16 ^ (col & 7)) << 3));
            const short8 bl = *reinterpret_cast<const short8*>(bb + (((4 + l16) ^ (col & 7)) << 3));
            #pragma unroll
            for (int mf = 0; mf < 4; ++mf) {
                acc[mf][nf] = __builtin_amdgcn_mfma_f32_16x16x32_bf16(ah[mf], bh, acc[mf][nf], 0, 0, 0);
                acc[mf][nf] = __builtin_amdgcn_mfma_f32_16x16x32_bf16(al[mf], bh, acc[mf][nf], 0, 0, 0);
                acc[mf][nf] = __builtin_amdgcn_mfma_f32_16x16x32_bf16(ah[mf], bl, acc[mf][nf], 0, 0, 0);
            }
        }
        __builtin_amdgcn_s_setprio(0);

        if (pf) WRITE_A(nxt)
        __syncthreads();
    }
    #undef LOAD_A
    #undef LOAD_B
    #undef WRITE_A

    // epilogue: power -> dB -> store + per-batch max
    const int batch = sig >> 1, ch = sig & 1;
    float lmax = -3.0e38f;
    #pragma unroll
    for (int mf = 0; mf < 4; ++mf)
        #pragma unroll
        for (int nf = 0; nf < 4; ++nf) {
            const int col = nt * 128 + wn * 64 + nf * 16 + l15;
            const int bin = col >> 1;
            #pragma unroll
            for (int r = 0; r < 4; ++r) {
                const float v  = acc[mf][nf][r];
                const float sq = v * v;
                const float p  = sq + __shfl_xor(sq, 1);
                if (!(lane & 1)) {
                    const int frame = f0 + wm * 64 + mf * 16 + l16 * 4 + r;
                    const float d = 10.0f * log10f(fmaxf(p, 1e-10f));
                    out[((long)(batch * NFILT + bin) * NFRAME + frame) * 2 + ch] = d;
                    lmax = fmaxf(lmax, d);
                }
            }
        }
    #pragma unroll
    for (int off = 32; off > 0; off >>= 1) lmax = fmaxf(lmax, __shfl_xor(lmax, off));
    if (lane == 0) atomicMax(&wmax[batch], f2key(lmax));
}

// ---------------------------------------------------------------------------
// Nyquist bin (512): block = 1 signal x 64 frames, x + coeffs staged in LDS.
// ---------------------------------------------------------------------------
__global__ __launch_bounds__(256, 2) void spec_nyq(
    const float* __restrict__ x, const float* __restrict__ kr,
    const float* __restrict__ ki, float* __restrict__ out,
    unsigned int* __restrict__ wmax)
{
    __shared__ float xs[17152];  // 63*256 + 1024
    __shared__ float kc[1024], ks[1024];
    const int sig = blockIdx.x >> 4, ft = blockIdx.x & 15;
    const int f0 = ft * 64;
    const long sb = (long)sig * LSRC;
    const int start = f0 * NHOP - PAD_L;
    for (int i = threadIdx.x; i < 17152; i += 256) {
        const int p = start + i;
        xs[i] = (p >= 0 && p < LSRC) ? x[sb + p] : 0.0f;
    }
    for (int t = threadIdx.x; t < 1024; t += 256) {
        kc[t] = kr[t * NFILT + 512];
        ks[t] = ki[t * NFILT + 512];
    }
    __syncthreads();
    const int fr = threadIdx.x >> 2, q = threadIdx.x & 3;
    const int rot = ((fr + q) & 7) * 4;   // bank rotation (sum order-invariant)
    float re = 0.0f, im = 0.0f;
    #pragma unroll 4
    for (int j = 0; j < 256; j += 4) {
        const int je = (j + rot) & 255;
        const float4 a = *reinterpret_cast<const float4*>(&xs[fr * 256 + q * 256 + je]);
        const float4 c = *reinterpret_cast<const float4*>(&kc[q * 256 + je]);
        const float4 s = *reinterpret_cast<const float4*>(&ks[q * 256 + je]);
        re = fmaf(a.x, c.x, re); re = fmaf(a.y, c.y, re);
        re = fmaf(a.z, c.z, re); re = fmaf(a.w, c.w, re);
        im = fmaf(a.x, s.x, im); im = fmaf(a.y, s.y, im);
        im = fmaf(a.z, s.z, im); im = fmaf(a.w, s.w, im);
    }
    re += __shfl_xor(re, 1); re += __shfl_xor(re, 2);
    im += __shfl_xor(im, 1); im += __shfl_xor(im, 2);
    const int batch = sig >> 1, ch = sig & 1;
    float lmax = -3.0e38f;
    if (q == 0) {
        const float p = re * re + im * im;
        const float d = 10.0f * log10f(fmaxf(p, 1e-10f));
        out[((long)(batch * NFILT + 512) * NFRAME + (f0 + fr)) * 2 + ch] = d;
        lmax = d;
    }
    #pragma unroll
    for (int off = 32; off > 0; off >>= 1) lmax = fmaxf(lmax, __shfl_xor(lmax, off));
    if ((threadIdx.x & 63) == 0) atomicMax(&wmax[batch], f2key(lmax));
}

// out = max(out - max_b, -80), vectorized float4
__global__ __launch_bounds__(256) void finalize(
    float* __restrict__ out, const unsigned int* __restrict__ wmax, long n4)
{
    const long stride = (long)gridDim.x * 256;
    for (long i4 = blockIdx.x * 256L + threadIdx.x; i4 < n4; i4 += stride) {
        const long i = i4 * 4;
        const int b  = (int)(i / PER_B);
        const float m = key2f(wmax[b]);
        float4 v = reinterpret_cast<float4*>(out)[i4];
        v.x = fmaxf(v.x - m, -80.0f);
        v.y = fmaxf(v.y - m, -80.0f);
        v.z = fmaxf(v.z - m, -80.0f);
        v.w = fmaxf(v.w - m, -80.0f);
        reinterpret_cast<float4*>(out)[i4] = v;
    }
}

// ---------------------------------------------------------------------------
// Fallback (proven fp32 vector path) if ws too small.
// ---------------------------------------------------------------------------
namespace fb {
constexpr int TILE_F = 32;
constexpr int SPAN   = (TILE_F - 1) * NHOP + NDFT;
}

__global__ __launch_bounds__(256) void spec_main_fb(
    const float* __restrict__ x, const float* __restrict__ kr,
    const float* __restrict__ ki, float* __restrict__ out,
    unsigned int* __restrict__ wmax)
{
    __shared__ float xs[fb::SPAN];
    const int s   = blockIdx.x;
    const int f0  = blockIdx.y * fb::TILE_F;
    const int tid = threadIdx.x;
    const long sig_base = (long)s * LSRC;
    const int start = f0 * NHOP - PAD_L;
    for (int i = tid; i < fb::SPAN; i += 256) {
        const int p = start + i;
        xs[i] = (p >= 0 && p < LSRC) ? x[sig_base + p] : 0.0f;
    }
    __syncthreads();
    const int b0 = tid, b1 = tid + 256;
    float ar0[fb::TILE_F], ai0[fb::TILE_F], ar1[fb::TILE_F], ai1[fb::TILE_F];
    #pragma unroll
    for (int f = 0; f < fb::TILE_F; ++f) { ar0[f]=0.f; ai0[f]=0.f; ar1[f]=0.f; ai1[f]=0.f; }
    #pragma unroll 1
    for (int t = 0; t < NDFT; t += 4) {
        float br0[4], bq0[4], br1[4], bq1[4];
        #pragma unroll
        for (int j = 0; j < 4; ++j) {
            br0[j] = kr[(t + j) * NFILT + b0]; bq0[j] = ki[(t + j) * NFILT + b0];
            br1[j] = kr[(t + j) * NFILT + b1]; bq1[j] = ki[(t + j) * NFILT + b1];
        }
        #pragma unroll
        for (int f = 0; f < fb::TILE_F; ++f) {
            const float4 a = *reinterpret_cast<const float4*>(&xs[t + NHOP * f]);
            ar0[f]=fmaf(a.x,br0[0],ar0[f]); ar0[f]=fmaf(a.y,br0[1],ar0[f]);
            ar0[f]=fmaf(a.z,br0[2],ar0[f]); ar0[f]=fmaf(a.w,br0[3],ar0[f]);
            ai0[f]=fmaf(a.x,bq0[0],ai0[f]); ai0[f]=fmaf(a.y,bq0[1],ai0[f]);
            ai0[f]=fmaf(a.z,bq0[2],ai0[f]); ai0[f]=fmaf(a.w,bq0[3],ai0[f]);
            ar1[f]=fmaf(a.x,br1[0],ar1[f]); ar1[f]=fmaf(a.y,br1[1],ar1[f]);
            ar1[f]=fmaf(a.z,br1[2],ar1[f]); ar1[f]=fmaf(a.w,br1[3],ar1[f]);
            ai1[f]=fmaf(a.x,bq1[0],ai1[f]); ai1[f]=fmaf(a.y,bq1[1],ai1[f]);
            ai1[f]=fmaf(a.z,bq1[2],ai1[f]); ai1[f]=fmaf(a.w,bq1[3],ai1[f]);
        }
    }
    const int b = s >> 1, ch = s & 1;
    float lmax = -3.0e38f;
    #pragma unroll
    for (int f = 0; f < fb::TILE_F; ++f) {
        const int frame = f0 + f;
        const float p0 = ar0[f]*ar0[f] + ai0[f]*ai0[f];
        const float p1 = ar1[f]*ar1[f] + ai1[f]*ai1[f];
        const float d0 = 10.0f * log10f(fmaxf(p0, 1e-10f));
        const float d1 = 10.0f * log10f(fmaxf(p1, 1e-10f));
        lmax = fmaxf(lmax, fmaxf(d0, d1));
        out[((long)(b * NFILT + b0) * NFRAME + frame) * 2 + ch] = d0;
        out[((long)(b * NFILT + b1) * NFRAME + frame) * 2 + ch] = d1;
    }
    #pragma unroll
    for (int off = 32; off > 0; off >>= 1) lmax = fmaxf(lmax, __shfl_xor(lmax, off));
    if ((tid & 63) == 0) atomicMax(&wmax[b], f2key(lmax));
}

__global__ __launch_bounds__(256) void spec_nyq_fb(
    const float* __restrict__ x, const float* __restrict__ kr,
    const float* __restrict__ ki, float* __restrict__ out,
    unsigned int* __restrict__ wmax)
{
    const int gid   = blockIdx.x * 256 + threadIdx.x;
    const int s     = gid >> 10;
    const int frame = gid & 1023;
    const float* xp = x + (long)s * LSRC;
    const int start = frame * NHOP - PAD_L;
    float re = 0.f, im = 0.f;
    for (int t = 0; t < NDFT; ++t) {
        const int idx = start + t;
        const float a = (idx >= 0 && idx < LSRC) ? xp[idx] : 0.0f;
        re = fmaf(a, kr[t * NFILT + 512], re);
        im = fmaf(a, ki[t * NFILT + 512], im);
    }
    const float p = re * re + im * im;
    const float d = 10.0f * log10f(fmaxf(p, 1e-10f));
    const int b = s >> 1, ch = s & 1;
    out[((long)(b * NFILT + 512) * NFRAME + frame) * 2 + ch] = d;
    float lmax = d;
    #pragma unroll
    for (int off = 32; off > 0; off >>= 1) lmax = fmaxf(lmax, __shfl_xor(lmax, off));
    if ((threadIdx.x & 63) == 0) atomicMax(&wmax[b], f2key(lmax));
}

extern "C" void kernel_launch(void* const* d_in, const int* in_sizes, int n_in,
                              void* d_out, int out_size, void* d_ws, size_t ws_size,
                              hipStream_t stream) {
    const float* x  = (const float*)d_in[0];
    const float* kr = (const float*)d_in[1];
    const float* ki = (const float*)d_in[2];
    float* out = (float*)d_out;
    const long n4 = (long)out_size / 4;

    if (ws_size >= WS_B_BYTES + 128) {
        unsigned short* wsB = (unsigned short*)d_ws;
        unsigned int* wmax  = (unsigned int*)((char*)d_ws + WS_B_BYTES);
        zero_ws<<<1, 64, 0, stream>>>(wmax);
        build_B<<<NT * KT, 256, 0, stream>>>(kr, ki, wsB);
        spec_gemm<<<dim3(512, NT), 256, 0, stream>>>(x, wsB, out, wmax);
        spec_nyq<<<1024, 256, 0, stream>>>(x, kr, ki, out, wmax);
        finalize<<<2048, 256, 0, stream>>>(out, wmax, n4);
    } else {
        unsigned int* wmax = (unsigned int*)d_ws;
        zero_ws<<<1, 64, 0, stream>>>(wmax);
        dim3 grid(64, NFRAME / fb::TILE_F);
        spec_main_fb<<<grid, 256, 0, stream>>>(x, kr, ki, out, wmax);
        spec_nyq_fb<<<(64 * NFRAME) / 256, 256, 0, stream>>>(x, kr, ki, out, wmax);
        finalize<<<2048, 256, 0, stream>>>(out, wmax, n4);
    }
}